// Round 1
// baseline (1240.872 us; speedup 1.0000x reference)
//
#include <hip/hip_runtime.h>
#include <cstdint>
#include <cstddef>

#define NN 30000
#define NE 480000

__device__ __forceinline__ float leakyf(float x){ return x > 0.f ? x : 0.2f * x; }
__device__ __forceinline__ float eluf(float x){ return x > 0.f ? x : expm1f(x); }

struct F4 { float x, y, z, w; };

__device__ __forceinline__ F4 ld4(const float* p){
  float4 v = *(const float4*)p;
  return F4{v.x, v.y, v.z, v.w};
}

// ---------------- CSR build ----------------

__global__ void zero_int_kernel(int* __restrict__ p, int n){
  int i = blockIdx.x * blockDim.x + threadIdx.x;
  if (i < n) p[i] = 0;
}

__global__ void count_kernel(const int* __restrict__ dst, int* __restrict__ deg, int E){
  int i = blockIdx.x * blockDim.x + threadIdx.x;
  if (i < E) atomicAdd(&deg[dst[i]], 1);
}

__global__ void scan_kernel(const int* __restrict__ deg, int* __restrict__ offs, int n){
  __shared__ int sh[1024];
  __shared__ int carry;
  int tid = threadIdx.x;
  if (tid == 0){ carry = 0; offs[0] = 0; }
  __syncthreads();
  for (int base = 0; base < n; base += 1024){
    int i = base + tid;
    int v = (i < n) ? deg[i] : 0;
    sh[tid] = v;
    __syncthreads();
    for (int o = 1; o < 1024; o <<= 1){
      int t = (tid >= o) ? sh[tid - o] : 0;
      __syncthreads();
      sh[tid] += t;
      __syncthreads();
    }
    int c = carry;
    int inc = sh[tid];
    int total = sh[1023];
    if (i < n) offs[i + 1] = c + inc;
    __syncthreads();
    if (tid == 0) carry = c + total;
    __syncthreads();
  }
}

__global__ void scatter_kernel(const int* __restrict__ src, const int* __restrict__ dst,
                               const int* __restrict__ et, const int* __restrict__ offs,
                               int* __restrict__ cursor, int* __restrict__ csr_src,
                               int* __restrict__ csr_et, int E){
  int i = blockIdx.x * blockDim.x + threadIdx.x;
  if (i < E){
    int d = dst[i];
    int pos = offs[d] + atomicAdd(&cursor[d], 1);
    csr_src[pos] = src[i];
    csr_et[pos]  = et[i];
  }
}

// ---------------- RGCN ----------------

// xb[n, b*64+o] = sum_i x[n,i] * basis[b, i, o]   (block = 256 threads, one node/block)
__global__ void xb_kernel(const float* __restrict__ x, const float* __restrict__ basis,
                          float* __restrict__ xb, int fin){
  int node = blockIdx.x;
  int t = threadIdx.x;
  int b = t >> 6, o = t & 63;
  const float* xr = x + (size_t)node * fin;
  const float* B  = basis + (size_t)b * fin * 64 + o;
  float acc = 0.f;
  for (int i = 0; i < fin; i++) acc += xr[i] * B[(size_t)i * 64];
  xb[(size_t)node * 256 + t] = acc;
}

// one wave per node: mean-aggregate basis-combined messages + root + bias + elu
__global__ void rgcn_agg_kernel(const float* __restrict__ xb, const float* __restrict__ xin,
                                const float* __restrict__ root, const float* __restrict__ brg,
                                const float* __restrict__ comp, const int* __restrict__ offs,
                                const int* __restrict__ csr_src, const int* __restrict__ csr_et,
                                float* __restrict__ hout, int fin){
  int wid  = (blockIdx.x * blockDim.x + threadIdx.x) >> 6;
  int lane = threadIdx.x & 63;
  if (wid >= NN) return;
  int n0 = offs[wid], n1 = offs[wid + 1];
  float acc = 0.f;
  for (int k = n0; k < n1; k++){
    int s = csr_src[k], e = csr_et[k];
    F4 cp = ld4(comp + (size_t)e * 4);
    const float* xs = xb + (size_t)s * 256 + lane;
    acc += cp.x * xs[0] + cp.y * xs[64] + cp.z * xs[128] + cp.w * xs[192];
  }
  int dg = n1 - n0;
  acc /= (float)(dg > 0 ? dg : 1);
  const float* xr = xin + (size_t)wid * fin;
  const float* rc = root + lane;
  for (int i = 0; i < fin; i++) acc += xr[i] * rc[(size_t)i * 64];
  acc += brg[lane];
  hout[(size_t)wid * 64 + lane] = eluf(acc);
}

// ---------------- GAT ----------------

// hW = h @ W (64 -> 256), fused attention logits. block = 256 (one node), wave = head.
__global__ void gat_lin1_kernel(const float* __restrict__ h, const float* __restrict__ W,
                                const float* __restrict__ atts, const float* __restrict__ attd,
                                float* __restrict__ hw, float* __restrict__ as_, float* __restrict__ ad_){
  int node = blockIdx.x;
  int t = threadIdx.x;
  const float* hr = h + (size_t)node * 64;
  const float* Wc = W + t;
  float acc = 0.f;
  #pragma unroll 8
  for (int i = 0; i < 64; i++) acc += hr[i] * Wc[(size_t)i * 256];
  hw[(size_t)node * 256 + t] = acc;
  int lane = t & 63, hh = t >> 6;
  float ps = acc * atts[t];
  float pd = acc * attd[t];
  #pragma unroll
  for (int o = 32; o; o >>= 1){ ps += __shfl_xor(ps, o); pd += __shfl_xor(pd, o); }
  if (lane == 0){ as_[node * 4 + hh] = ps; ad_[node * 4 + hh] = pd; }
}

// GAT1 softmax-aggregate. one wave per node, lane = channel, 4 heads per lane.
__global__ void gat1_agg_kernel(const float* __restrict__ hw, const float* __restrict__ as_,
                                const float* __restrict__ ad_, const float* __restrict__ bias,
                                const int* __restrict__ offs, const int* __restrict__ csr_src,
                                float* __restrict__ out){
  int wid  = (blockIdx.x * blockDim.x + threadIdx.x) >> 6;
  int lane = threadIdx.x & 63;
  if (wid >= NN) return;
  int n0 = offs[wid], n1 = offs[wid + 1];
  F4 adn = ld4(ad_ + (size_t)wid * 4);
  F4 asn = ld4(as_ + (size_t)wid * 4);
  F4 es{leakyf(asn.x + adn.x), leakyf(asn.y + adn.y), leakyf(asn.z + adn.z), leakyf(asn.w + adn.w)};
  F4 m = es;
  // pass A: max over in-edges (lanes strided over edges)
  for (int k = n0 + lane; k < n1; k += 64){
    int s = csr_src[k];
    F4 a = ld4(as_ + (size_t)s * 4);
    m.x = fmaxf(m.x, leakyf(a.x + adn.x));
    m.y = fmaxf(m.y, leakyf(a.y + adn.y));
    m.z = fmaxf(m.z, leakyf(a.z + adn.z));
    m.w = fmaxf(m.w, leakyf(a.w + adn.w));
  }
  #pragma unroll
  for (int o = 32; o; o >>= 1){
    m.x = fmaxf(m.x, __shfl_xor(m.x, o));
    m.y = fmaxf(m.y, __shfl_xor(m.y, o));
    m.z = fmaxf(m.z, __shfl_xor(m.z, o));
    m.w = fmaxf(m.w, __shfl_xor(m.w, o));
  }
  F4 ps{expf(es.x - m.x), expf(es.y - m.y), expf(es.z - m.z), expf(es.w - m.w)};
  F4 den = ps;  // self-loop term; all lanes accumulate identically below
  float a0 = 0.f, a1 = 0.f, a2 = 0.f, a3 = 0.f;
  // pass B: whole wave walks each edge; p recomputed (broadcast), channels in lanes
  for (int k = n0; k < n1; k++){
    int s = csr_src[k];
    F4 a = ld4(as_ + (size_t)s * 4);
    F4 p{expf(leakyf(a.x + adn.x) - m.x), expf(leakyf(a.y + adn.y) - m.y),
         expf(leakyf(a.z + adn.z) - m.z), expf(leakyf(a.w + adn.w) - m.w)};
    den.x += p.x; den.y += p.y; den.z += p.z; den.w += p.w;
    const float* hb = hw + (size_t)s * 256 + lane;
    a0 += p.x * hb[0];  a1 += p.y * hb[64];
    a2 += p.z * hb[128]; a3 += p.w * hb[192];
  }
  const float* hn = hw + (size_t)wid * 256 + lane;
  a0 += ps.x * hn[0];  a1 += ps.y * hn[64];
  a2 += ps.z * hn[128]; a3 += ps.w * hn[192];
  float* ob = out + (size_t)wid * 256;
  ob[lane]       = eluf(a0 / den.x + bias[lane]);
  ob[64 + lane]  = eluf(a1 / den.y + bias[64 + lane]);
  ob[128 + lane] = eluf(a2 / den.z + bias[128 + lane]);
  ob[192 + lane] = eluf(a3 / den.w + bias[192 + lane]);
}

// hW2 = h3 @ Wg2 (64 -> 12), fused logits. one wave per node, lanes 0..11 active for GEMV.
__global__ void gat_lin2_kernel(const float* __restrict__ h, const float* __restrict__ W,
                                const float* __restrict__ atts, const float* __restrict__ attd,
                                float* __restrict__ hw, float* __restrict__ as_, float* __restrict__ ad_){
  int wid  = (blockIdx.x * blockDim.x + threadIdx.x) >> 6;
  int lane = threadIdx.x & 63;
  if (wid >= NN) return;
  float acc = 0.f;
  if (lane < 12){
    const float* hr = h + (size_t)wid * 64;
    const float* Wc = W + lane;
    #pragma unroll 8
    for (int i = 0; i < 64; i++) acc += hr[i] * Wc[(size_t)i * 12];
    hw[(size_t)wid * 12 + lane] = acc;
  }
  float ts = (lane < 12) ? acc * atts[lane] : 0.f;
  float td = (lane < 12) ? acc * attd[lane] : 0.f;
  int b = (lane < 4) ? lane * 3 : 0;
  float s0 = __shfl(ts, b) + __shfl(ts, b + 1) + __shfl(ts, b + 2);
  float d0 = __shfl(td, b) + __shfl(td, b + 1) + __shfl(td, b + 2);
  if (lane < 4){ as_[wid * 4 + lane] = s0; ad_[wid * 4 + lane] = d0; }
}

// GAT2 (mean over heads) + mean over classes + tanh. one wave per node, lanes over edges.
__global__ void gat2_final_kernel(const float* __restrict__ hw, const float* __restrict__ as_,
                                  const float* __restrict__ ad_, const float* __restrict__ bg2,
                                  const int* __restrict__ offs, const int* __restrict__ csr_src,
                                  float* __restrict__ out){
  int wid  = (blockIdx.x * blockDim.x + threadIdx.x) >> 6;
  int lane = threadIdx.x & 63;
  if (wid >= NN) return;
  int n0 = offs[wid], n1 = offs[wid + 1];
  F4 adn = ld4(ad_ + (size_t)wid * 4);
  F4 asn = ld4(as_ + (size_t)wid * 4);
  F4 es{leakyf(asn.x + adn.x), leakyf(asn.y + adn.y), leakyf(asn.z + adn.z), leakyf(asn.w + adn.w)};
  F4 m = es;
  for (int k = n0 + lane; k < n1; k += 64){
    int s = csr_src[k];
    F4 a = ld4(as_ + (size_t)s * 4);
    m.x = fmaxf(m.x, leakyf(a.x + adn.x));
    m.y = fmaxf(m.y, leakyf(a.y + adn.y));
    m.z = fmaxf(m.z, leakyf(a.z + adn.z));
    m.w = fmaxf(m.w, leakyf(a.w + adn.w));
  }
  #pragma unroll
  for (int o = 32; o; o >>= 1){
    m.x = fmaxf(m.x, __shfl_xor(m.x, o));
    m.y = fmaxf(m.y, __shfl_xor(m.y, o));
    m.z = fmaxf(m.z, __shfl_xor(m.z, o));
    m.w = fmaxf(m.w, __shfl_xor(m.w, o));
  }
  F4 ps{expf(es.x - m.x), expf(es.y - m.y), expf(es.z - m.z), expf(es.w - m.w)};
  float acc[12];
  #pragma unroll
  for (int j = 0; j < 12; j++) acc[j] = 0.f;
  F4 denp{0.f, 0.f, 0.f, 0.f};
  for (int k = n0 + lane; k < n1; k += 64){
    int s = csr_src[k];
    F4 a = ld4(as_ + (size_t)s * 4);
    F4 p{expf(leakyf(a.x + adn.x) - m.x), expf(leakyf(a.y + adn.y) - m.y),
         expf(leakyf(a.z + adn.z) - m.z), expf(leakyf(a.w + adn.w) - m.w)};
    denp.x += p.x; denp.y += p.y; denp.z += p.z; denp.w += p.w;
    const float* hb = hw + (size_t)s * 12;
    F4 h0 = ld4(hb), h1 = ld4(hb + 4), h2 = ld4(hb + 8);
    acc[0] += p.x * h0.x; acc[1]  += p.x * h0.y; acc[2]  += p.x * h0.z;
    acc[3] += p.y * h0.w; acc[4]  += p.y * h1.x; acc[5]  += p.y * h1.y;
    acc[6] += p.z * h1.z; acc[7]  += p.z * h1.w; acc[8]  += p.z * h2.x;
    acc[9] += p.w * h2.y; acc[10] += p.w * h2.z; acc[11] += p.w * h2.w;
  }
  #pragma unroll
  for (int o = 32; o; o >>= 1){
    denp.x += __shfl_xor(denp.x, o);
    denp.y += __shfl_xor(denp.y, o);
    denp.z += __shfl_xor(denp.z, o);
    denp.w += __shfl_xor(denp.w, o);
    #pragma unroll
    for (int j = 0; j < 12; j++) acc[j] += __shfl_xor(acc[j], o);
  }
  if (lane == 0){
    const float* hn = hw + (size_t)wid * 12;
    float dn[4]  = {denp.x + ps.x, denp.y + ps.y, denp.z + ps.z, denp.w + ps.w};
    float psv[4] = {ps.x, ps.y, ps.z, ps.w};
    float tot = 0.f;
    #pragma unroll
    for (int h_ = 0; h_ < 4; h_++){
      #pragma unroll
      for (int c = 0; c < 3; c++){
        float num = acc[h_ * 3 + c] + psv[h_] * hn[h_ * 3 + c];
        tot += num / dn[h_];
      }
    }
    tot = tot / 12.f + (bg2[0] + bg2[1] + bg2[2]) / 3.f;
    out[wid] = tanhf(tot);
  }
}

// ---------------- launch ----------------

extern "C" void kernel_launch(void* const* d_in, const int* in_sizes, int n_in,
                              void* d_out, int out_size, void* d_ws, size_t ws_size,
                              hipStream_t stream){
  const float* x      = (const float*)d_in[0];
  const int*   ei     = (const int*)d_in[1];
  const int*   et     = (const int*)d_in[2];
  const float* basis1 = (const float*)d_in[3];
  const float* comp1  = (const float*)d_in[4];
  const float* root1  = (const float*)d_in[5];
  const float* brg1   = (const float*)d_in[6];
  const float* Wg1    = (const float*)d_in[7];
  const float* atts1  = (const float*)d_in[8];
  const float* attd1  = (const float*)d_in[9];
  const float* bg1    = (const float*)d_in[10];
  const float* basis2 = (const float*)d_in[11];
  const float* comp2  = (const float*)d_in[12];
  const float* root2  = (const float*)d_in[13];
  const float* brg2   = (const float*)d_in[14];
  const float* Wg2    = (const float*)d_in[15];
  const float* atts2  = (const float*)d_in[16];
  const float* attd2  = (const float*)d_in[17];
  const float* bg2    = (const float*)d_in[18];
  float* out = (float*)d_out;

  const int* src = ei;
  const int* dst = ei + NE;

  char* ws = (char*)d_ws;
  size_t off = 0;
  auto alloc = [&](size_t bytes) -> void* {
    void* p = ws + off;
    off = (off + bytes + 255) & ~(size_t)255;
    return p;
  };
  int*   deg     = (int*)alloc((size_t)NN * 4);
  int*   cursor  = (int*)alloc((size_t)NN * 4);
  int*   offs    = (int*)alloc((size_t)(NN + 1) * 4);
  int*   csr_src = (int*)alloc((size_t)NE * 4);
  int*   csr_et  = (int*)alloc((size_t)NE * 4);
  float* bufA    = (float*)alloc((size_t)NN * 256 * 4); // xb1 -> hW1 -> xb2
  float* h1      = (float*)alloc((size_t)NN * 64 * 4);
  float* h2      = (float*)alloc((size_t)NN * 256 * 4);
  float* h3      = (float*)alloc((size_t)NN * 64 * 4);
  float* hw2     = (float*)alloc((size_t)NN * 12 * 4);
  float* as1     = (float*)alloc((size_t)NN * 4 * 4);
  float* ad1     = (float*)alloc((size_t)NN * 4 * 4);
  float* as2     = (float*)alloc((size_t)NN * 4 * 4);
  float* ad2     = (float*)alloc((size_t)NN * 4 * 4);
  (void)ws_size; (void)n_in; (void)in_sizes; (void)out_size;

  const int BLK = 256;
  int gridN  = (NN + BLK - 1) / BLK;
  int gridE  = (NE + BLK - 1) / BLK;
  int gridW  = (NN + 3) / 4;  // 4 waves/block, 1 node/wave

  // CSR build
  zero_int_kernel<<<gridN, BLK, 0, stream>>>(deg, NN);
  zero_int_kernel<<<gridN, BLK, 0, stream>>>(cursor, NN);
  count_kernel<<<gridE, BLK, 0, stream>>>(dst, deg, NE);
  scan_kernel<<<1, 1024, 0, stream>>>(deg, offs, NN);
  scatter_kernel<<<gridE, BLK, 0, stream>>>(src, dst, et, offs, cursor, csr_src, csr_et, NE);

  // Layer 1: RGCN (32 -> 64) + elu
  xb_kernel<<<NN, BLK, 0, stream>>>(x, basis1, bufA, 32);
  rgcn_agg_kernel<<<gridW, BLK, 0, stream>>>(bufA, x, root1, brg1, comp1, offs, csr_src, csr_et, h1, 32);

  // Layer 2: GAT (64 -> 256 concat) + elu
  gat_lin1_kernel<<<NN, BLK, 0, stream>>>(h1, Wg1, atts1, attd1, bufA, as1, ad1);
  gat1_agg_kernel<<<gridW, BLK, 0, stream>>>(bufA, as1, ad1, bg1, offs, csr_src, h2);

  // Layer 3: RGCN (256 -> 64) + elu
  xb_kernel<<<NN, BLK, 0, stream>>>(h2, basis2, bufA, 256);
  rgcn_agg_kernel<<<gridW, BLK, 0, stream>>>(bufA, h2, root2, brg2, comp2, offs, csr_src, csr_et, h3, 256);

  // Layer 4: GAT (64 -> 4x3, mean heads) + mean classes + tanh
  gat_lin2_kernel<<<gridW, BLK, 0, stream>>>(h3, Wg2, atts2, attd2, hw2, as2, ad2);
  gat2_final_kernel<<<gridW, BLK, 0, stream>>>(hw2, as2, ad2, bg2, offs, csr_src, out);
}

// Round 2
// 852.813 us; speedup vs baseline: 1.4550x; 1.4550x over previous
//
#include <hip/hip_runtime.h>
#include <cstdint>
#include <cstddef>

#define NN 30000
#define NE 480000

__device__ __forceinline__ float leakyf(float x){ return x > 0.f ? x : 0.2f * x; }
__device__ __forceinline__ float eluf(float x){ return x > 0.f ? x : expm1f(x); }

struct F4 { float x, y, z, w; };

__device__ __forceinline__ F4 ld4(const float* p){
  float4 v = *(const float4*)p;
  return F4{v.x, v.y, v.z, v.w};
}

// ---------------- CSR build ----------------

__global__ void zero_int_kernel(int* __restrict__ p, int n){
  int i = blockIdx.x * blockDim.x + threadIdx.x;
  if (i < n) p[i] = 0;
}

__global__ void count_kernel(const int* __restrict__ dst, int* __restrict__ deg, int E){
  int i = blockIdx.x * blockDim.x + threadIdx.x;
  if (i < E) atomicAdd(&deg[dst[i]], 1);
}

__global__ void scan_kernel(const int* __restrict__ deg, int* __restrict__ offs, int n){
  __shared__ int sh[1024];
  __shared__ int carry;
  int tid = threadIdx.x;
  if (tid == 0){ carry = 0; offs[0] = 0; }
  __syncthreads();
  for (int base = 0; base < n; base += 1024){
    int i = base + tid;
    int v = (i < n) ? deg[i] : 0;
    sh[tid] = v;
    __syncthreads();
    for (int o = 1; o < 1024; o <<= 1){
      int t = (tid >= o) ? sh[tid - o] : 0;
      __syncthreads();
      sh[tid] += t;
      __syncthreads();
    }
    int c = carry;
    int inc = sh[tid];
    int total = sh[1023];
    if (i < n) offs[i + 1] = c + inc;
    __syncthreads();
    if (tid == 0) carry = c + total;
    __syncthreads();
  }
}

__global__ void scatter_kernel(const int* __restrict__ src, const int* __restrict__ dst,
                               const int* __restrict__ et, const int* __restrict__ offs,
                               int* __restrict__ cursor, int* __restrict__ csr_src,
                               int* __restrict__ csr_et, int E){
  int i = blockIdx.x * blockDim.x + threadIdx.x;
  if (i < E){
    int d = dst[i];
    int pos = offs[d] + atomicAdd(&cursor[d], 1);
    csr_src[pos] = src[i];
    csr_et[pos]  = et[i];
  }
}

// ---------------- register-blocked GEMM: Y[n, cg*64+c] = sum_k X[n,k] * W[k, cg*64+c] ----
// thread = row (node), blockIdx.y = column group cg (64 cols), acc[64] in VGPRs.
// W row addresses are wave-uniform -> scalar/broadcast loads.
// Optionally fuses the GAT attention logits (cols of group cg = channels of head cg).

template<int FIN, bool ATT>
__global__ __launch_bounds__(256) void gemm_cols64_kernel(
    const float* __restrict__ X, const float* __restrict__ Wb,
    int wstride, int wblock,
    const float* __restrict__ atts, const float* __restrict__ attd,
    float* __restrict__ Y, float* __restrict__ as_, float* __restrict__ ad_)
{
  int node = blockIdx.x * 256 + threadIdx.x;
  int cg = blockIdx.y;
  if (node >= NN) return;
  const float* W  = Wb + (size_t)cg * wblock;
  const float* xr = X + (size_t)node * FIN;
  float acc[64];
  #pragma unroll
  for (int c = 0; c < 64; c++) acc[c] = 0.f;
  for (int k0 = 0; k0 < FIN; k0 += 16){
    float xv[16];
    #pragma unroll
    for (int j = 0; j < 4; j++){
      float4 v = *(const float4*)(xr + k0 + j * 4);
      xv[j*4] = v.x; xv[j*4+1] = v.y; xv[j*4+2] = v.z; xv[j*4+3] = v.w;
    }
    #pragma unroll 4
    for (int kk = 0; kk < 16; kk++){
      const float* Wr = W + (size_t)(k0 + kk) * wstride;
      float xk = xv[kk];
      #pragma unroll
      for (int c = 0; c < 64; c += 4){
        float4 bv = *(const float4*)(Wr + c);
        acc[c]   += xk * bv.x;
        acc[c+1] += xk * bv.y;
        acc[c+2] += xk * bv.z;
        acc[c+3] += xk * bv.w;
      }
    }
  }
  float* yr = Y + (size_t)node * 256 + cg * 64;
  #pragma unroll
  for (int c = 0; c < 64; c += 4)
    *(float4*)(yr + c) = make_float4(acc[c], acc[c+1], acc[c+2], acc[c+3]);
  if (ATT){
    float ps = 0.f, pd = 0.f;
    const float* pa = atts + cg * 64;
    const float* pb = attd + cg * 64;
    #pragma unroll
    for (int c = 0; c < 64; c++){ ps += acc[c] * pa[c]; pd += acc[c] * pb[c]; }
    as_[node * 4 + cg] = ps;
    ad_[node * 4 + cg] = pd;
  }
}

// ---------------- RGCN aggregate ----------------

// one wave per node: mean-aggregate basis-combined messages + root + bias + elu
__global__ void rgcn_agg_kernel(const float* __restrict__ xb, const float* __restrict__ xin,
                                const float* __restrict__ root, const float* __restrict__ brg,
                                const float* __restrict__ comp, const int* __restrict__ offs,
                                const int* __restrict__ csr_src, const int* __restrict__ csr_et,
                                float* __restrict__ hout, int fin){
  int wid  = (blockIdx.x * blockDim.x + threadIdx.x) >> 6;
  int lane = threadIdx.x & 63;
  if (wid >= NN) return;
  int n0 = offs[wid], n1 = offs[wid + 1];
  float acc = 0.f;
  for (int k = n0; k < n1; k++){
    int s = csr_src[k], e = csr_et[k];
    F4 cp = ld4(comp + (size_t)e * 4);
    const float* xs = xb + (size_t)s * 256 + lane;
    acc += cp.x * xs[0] + cp.y * xs[64] + cp.z * xs[128] + cp.w * xs[192];
  }
  int dg = n1 - n0;
  acc /= (float)(dg > 0 ? dg : 1);
  const float* xr = xin + (size_t)wid * fin;
  const float* rc = root + lane;
  for (int i = 0; i < fin; i++) acc += xr[i] * rc[(size_t)i * 64];
  acc += brg[lane];
  hout[(size_t)wid * 64 + lane] = eluf(acc);
}

// ---------------- GAT ----------------

// GAT1 softmax-aggregate. one wave per node, lane = channel, 4 heads per lane.
__global__ void gat1_agg_kernel(const float* __restrict__ hw, const float* __restrict__ as_,
                                const float* __restrict__ ad_, const float* __restrict__ bias,
                                const int* __restrict__ offs, const int* __restrict__ csr_src,
                                float* __restrict__ out){
  int wid  = (blockIdx.x * blockDim.x + threadIdx.x) >> 6;
  int lane = threadIdx.x & 63;
  if (wid >= NN) return;
  int n0 = offs[wid], n1 = offs[wid + 1];
  F4 adn = ld4(ad_ + (size_t)wid * 4);
  F4 asn = ld4(as_ + (size_t)wid * 4);
  F4 es{leakyf(asn.x + adn.x), leakyf(asn.y + adn.y), leakyf(asn.z + adn.z), leakyf(asn.w + adn.w)};
  F4 m = es;
  for (int k = n0 + lane; k < n1; k += 64){
    int s = csr_src[k];
    F4 a = ld4(as_ + (size_t)s * 4);
    m.x = fmaxf(m.x, leakyf(a.x + adn.x));
    m.y = fmaxf(m.y, leakyf(a.y + adn.y));
    m.z = fmaxf(m.z, leakyf(a.z + adn.z));
    m.w = fmaxf(m.w, leakyf(a.w + adn.w));
  }
  #pragma unroll
  for (int o = 32; o; o >>= 1){
    m.x = fmaxf(m.x, __shfl_xor(m.x, o));
    m.y = fmaxf(m.y, __shfl_xor(m.y, o));
    m.z = fmaxf(m.z, __shfl_xor(m.z, o));
    m.w = fmaxf(m.w, __shfl_xor(m.w, o));
  }
  F4 ps{expf(es.x - m.x), expf(es.y - m.y), expf(es.z - m.z), expf(es.w - m.w)};
  F4 den = ps;
  float a0 = 0.f, a1 = 0.f, a2 = 0.f, a3 = 0.f;
  for (int k = n0; k < n1; k++){
    int s = csr_src[k];
    F4 a = ld4(as_ + (size_t)s * 4);
    F4 p{expf(leakyf(a.x + adn.x) - m.x), expf(leakyf(a.y + adn.y) - m.y),
         expf(leakyf(a.z + adn.z) - m.z), expf(leakyf(a.w + adn.w) - m.w)};
    den.x += p.x; den.y += p.y; den.z += p.z; den.w += p.w;
    const float* hb = hw + (size_t)s * 256 + lane;
    a0 += p.x * hb[0];  a1 += p.y * hb[64];
    a2 += p.z * hb[128]; a3 += p.w * hb[192];
  }
  const float* hn = hw + (size_t)wid * 256 + lane;
  a0 += ps.x * hn[0];  a1 += ps.y * hn[64];
  a2 += ps.z * hn[128]; a3 += ps.w * hn[192];
  float* ob = out + (size_t)wid * 256;
  ob[lane]       = eluf(a0 / den.x + bias[lane]);
  ob[64 + lane]  = eluf(a1 / den.y + bias[64 + lane]);
  ob[128 + lane] = eluf(a2 / den.z + bias[128 + lane]);
  ob[192 + lane] = eluf(a3 / den.w + bias[192 + lane]);
}

// hW2 = h3 @ Wg2 (64 -> 12), fused logits. one wave per node, lanes 0..11 active for GEMV.
__global__ void gat_lin2_kernel(const float* __restrict__ h, const float* __restrict__ W,
                                const float* __restrict__ atts, const float* __restrict__ attd,
                                float* __restrict__ hw, float* __restrict__ as_, float* __restrict__ ad_){
  int wid  = (blockIdx.x * blockDim.x + threadIdx.x) >> 6;
  int lane = threadIdx.x & 63;
  if (wid >= NN) return;
  float acc = 0.f;
  if (lane < 12){
    const float* hr = h + (size_t)wid * 64;
    const float* Wc = W + lane;
    #pragma unroll 8
    for (int i = 0; i < 64; i++) acc += hr[i] * Wc[(size_t)i * 12];
    hw[(size_t)wid * 12 + lane] = acc;
  }
  float ts = (lane < 12) ? acc * atts[lane] : 0.f;
  float td = (lane < 12) ? acc * attd[lane] : 0.f;
  int b = (lane < 4) ? lane * 3 : 0;
  float s0 = __shfl(ts, b) + __shfl(ts, b + 1) + __shfl(ts, b + 2);
  float d0 = __shfl(td, b) + __shfl(td, b + 1) + __shfl(td, b + 2);
  if (lane < 4){ as_[wid * 4 + lane] = s0; ad_[wid * 4 + lane] = d0; }
}

// GAT2 (mean over heads) + mean over classes + tanh. one wave per node, lanes over edges.
__global__ void gat2_final_kernel(const float* __restrict__ hw, const float* __restrict__ as_,
                                  const float* __restrict__ ad_, const float* __restrict__ bg2,
                                  const int* __restrict__ offs, const int* __restrict__ csr_src,
                                  float* __restrict__ out){
  int wid  = (blockIdx.x * blockDim.x + threadIdx.x) >> 6;
  int lane = threadIdx.x & 63;
  if (wid >= NN) return;
  int n0 = offs[wid], n1 = offs[wid + 1];
  F4 adn = ld4(ad_ + (size_t)wid * 4);
  F4 asn = ld4(as_ + (size_t)wid * 4);
  F4 es{leakyf(asn.x + adn.x), leakyf(asn.y + adn.y), leakyf(asn.z + adn.z), leakyf(asn.w + adn.w)};
  F4 m = es;
  for (int k = n0 + lane; k < n1; k += 64){
    int s = csr_src[k];
    F4 a = ld4(as_ + (size_t)s * 4);
    m.x = fmaxf(m.x, leakyf(a.x + adn.x));
    m.y = fmaxf(m.y, leakyf(a.y + adn.y));
    m.z = fmaxf(m.z, leakyf(a.z + adn.z));
    m.w = fmaxf(m.w, leakyf(a.w + adn.w));
  }
  #pragma unroll
  for (int o = 32; o; o >>= 1){
    m.x = fmaxf(m.x, __shfl_xor(m.x, o));
    m.y = fmaxf(m.y, __shfl_xor(m.y, o));
    m.z = fmaxf(m.z, __shfl_xor(m.z, o));
    m.w = fmaxf(m.w, __shfl_xor(m.w, o));
  }
  F4 ps{expf(es.x - m.x), expf(es.y - m.y), expf(es.z - m.z), expf(es.w - m.w)};
  float acc[12];
  #pragma unroll
  for (int j = 0; j < 12; j++) acc[j] = 0.f;
  F4 denp{0.f, 0.f, 0.f, 0.f};
  for (int k = n0 + lane; k < n1; k += 64){
    int s = csr_src[k];
    F4 a = ld4(as_ + (size_t)s * 4);
    F4 p{expf(leakyf(a.x + adn.x) - m.x), expf(leakyf(a.y + adn.y) - m.y),
         expf(leakyf(a.z + adn.z) - m.z), expf(leakyf(a.w + adn.w) - m.w)};
    denp.x += p.x; denp.y += p.y; denp.z += p.z; denp.w += p.w;
    const float* hb = hw + (size_t)s * 12;
    F4 h0 = ld4(hb), h1 = ld4(hb + 4), h2 = ld4(hb + 8);
    acc[0] += p.x * h0.x; acc[1]  += p.x * h0.y; acc[2]  += p.x * h0.z;
    acc[3] += p.y * h0.w; acc[4]  += p.y * h1.x; acc[5]  += p.y * h1.y;
    acc[6] += p.z * h1.z; acc[7]  += p.z * h1.w; acc[8]  += p.z * h2.x;
    acc[9] += p.w * h2.y; acc[10] += p.w * h2.z; acc[11] += p.w * h2.w;
  }
  #pragma unroll
  for (int o = 32; o; o >>= 1){
    denp.x += __shfl_xor(denp.x, o);
    denp.y += __shfl_xor(denp.y, o);
    denp.z += __shfl_xor(denp.z, o);
    denp.w += __shfl_xor(denp.w, o);
    #pragma unroll
    for (int j = 0; j < 12; j++) acc[j] += __shfl_xor(acc[j], o);
  }
  if (lane == 0){
    const float* hn = hw + (size_t)wid * 12;
    float dn[4]  = {denp.x + ps.x, denp.y + ps.y, denp.z + ps.z, denp.w + ps.w};
    float psv[4] = {ps.x, ps.y, ps.z, ps.w};
    float tot = 0.f;
    #pragma unroll
    for (int h_ = 0; h_ < 4; h_++){
      #pragma unroll
      for (int c = 0; c < 3; c++){
        float num = acc[h_ * 3 + c] + psv[h_] * hn[h_ * 3 + c];
        tot += num / dn[h_];
      }
    }
    tot = tot / 12.f + (bg2[0] + bg2[1] + bg2[2]) / 3.f;
    out[wid] = tanhf(tot);
  }
}

// ---------------- launch ----------------

extern "C" void kernel_launch(void* const* d_in, const int* in_sizes, int n_in,
                              void* d_out, int out_size, void* d_ws, size_t ws_size,
                              hipStream_t stream){
  const float* x      = (const float*)d_in[0];
  const int*   ei     = (const int*)d_in[1];
  const int*   et     = (const int*)d_in[2];
  const float* basis1 = (const float*)d_in[3];
  const float* comp1  = (const float*)d_in[4];
  const float* root1  = (const float*)d_in[5];
  const float* brg1   = (const float*)d_in[6];
  const float* Wg1    = (const float*)d_in[7];
  const float* atts1  = (const float*)d_in[8];
  const float* attd1  = (const float*)d_in[9];
  const float* bg1    = (const float*)d_in[10];
  const float* basis2 = (const float*)d_in[11];
  const float* comp2  = (const float*)d_in[12];
  const float* root2  = (const float*)d_in[13];
  const float* brg2   = (const float*)d_in[14];
  const float* Wg2    = (const float*)d_in[15];
  const float* atts2  = (const float*)d_in[16];
  const float* attd2  = (const float*)d_in[17];
  const float* bg2    = (const float*)d_in[18];
  float* out = (float*)d_out;

  const int* src = ei;
  const int* dst = ei + NE;

  char* ws = (char*)d_ws;
  size_t off = 0;
  auto alloc = [&](size_t bytes) -> void* {
    void* p = ws + off;
    off = (off + bytes + 255) & ~(size_t)255;
    return p;
  };
  int*   deg     = (int*)alloc((size_t)NN * 4);
  int*   cursor  = (int*)alloc((size_t)NN * 4);
  int*   offs    = (int*)alloc((size_t)(NN + 1) * 4);
  int*   csr_src = (int*)alloc((size_t)NE * 4);
  int*   csr_et  = (int*)alloc((size_t)NE * 4);
  float* bufA    = (float*)alloc((size_t)NN * 256 * 4); // xb1 -> hW1 -> xb2
  float* h1      = (float*)alloc((size_t)NN * 64 * 4);
  float* h2      = (float*)alloc((size_t)NN * 256 * 4);
  float* h3      = (float*)alloc((size_t)NN * 64 * 4);
  float* hw2     = (float*)alloc((size_t)NN * 12 * 4);
  float* as1     = (float*)alloc((size_t)NN * 4 * 4);
  float* ad1     = (float*)alloc((size_t)NN * 4 * 4);
  float* as2     = (float*)alloc((size_t)NN * 4 * 4);
  float* ad2     = (float*)alloc((size_t)NN * 4 * 4);
  (void)ws_size; (void)n_in; (void)in_sizes; (void)out_size;

  const int BLK = 256;
  int gridN  = (NN + BLK - 1) / BLK;
  int gridE  = (NE + BLK - 1) / BLK;
  int gridW  = (NN + 3) / 4;            // 4 waves/block, 1 node/wave
  dim3 gridG((NN + 255) / 256, 4);      // GEMM: row groups x col groups

  // CSR build
  zero_int_kernel<<<gridN, BLK, 0, stream>>>(deg, NN);
  zero_int_kernel<<<gridN, BLK, 0, stream>>>(cursor, NN);
  count_kernel<<<gridE, BLK, 0, stream>>>(dst, deg, NE);
  scan_kernel<<<1, 1024, 0, stream>>>(deg, offs, NN);
  scatter_kernel<<<gridE, BLK, 0, stream>>>(src, dst, et, offs, cursor, csr_src, csr_et, NE);

  // Layer 1: RGCN (32 -> 64) + elu
  gemm_cols64_kernel<32, false><<<gridG, BLK, 0, stream>>>(
      x, basis1, 64, 32 * 64, nullptr, nullptr, bufA, nullptr, nullptr);
  rgcn_agg_kernel<<<gridW, BLK, 0, stream>>>(bufA, x, root1, brg1, comp1, offs, csr_src, csr_et, h1, 32);

  // Layer 2: GAT (64 -> 256 concat) + elu  (linear fused with attention logits)
  gemm_cols64_kernel<64, true><<<gridG, BLK, 0, stream>>>(
      h1, Wg1, 256, 64, atts1, attd1, bufA, as1, ad1);
  gat1_agg_kernel<<<gridW, BLK, 0, stream>>>(bufA, as1, ad1, bg1, offs, csr_src, h2);

  // Layer 3: RGCN (256 -> 64) + elu
  gemm_cols64_kernel<256, false><<<gridG, BLK, 0, stream>>>(
      h2, basis2, 64, 256 * 64, nullptr, nullptr, bufA, nullptr, nullptr);
  rgcn_agg_kernel<<<gridW, BLK, 0, stream>>>(bufA, h2, root2, brg2, comp2, offs, csr_src, csr_et, h3, 256);

  // Layer 4: GAT (64 -> 4x3, mean heads) + mean classes + tanh
  gat_lin2_kernel<<<gridW, BLK, 0, stream>>>(h3, Wg2, atts2, attd2, hw2, as2, ad2);
  gat2_final_kernel<<<gridW, BLK, 0, stream>>>(hw2, as2, ad2, bg2, offs, csr_src, out);
}

// Round 3
// 605.165 us; speedup vs baseline: 2.0505x; 1.4092x over previous
//
#include <hip/hip_runtime.h>
#include <cstdint>
#include <cstddef>

#define NN 30000
#define NE 480000

__device__ __forceinline__ float leakyf(float x){ return x > 0.f ? x : 0.2f * x; }
__device__ __forceinline__ float eluf(float x){ return x > 0.f ? x : expm1f(x); }

struct F4 { float x, y, z, w; };

__device__ __forceinline__ F4 ld4(const float* p){
  float4 v = *(const float4*)p;
  return F4{v.x, v.y, v.z, v.w};
}

// ---------------- CSR build ----------------

__global__ void zero_int_kernel(int* __restrict__ p, int n){
  int i = blockIdx.x * blockDim.x + threadIdx.x;
  if (i < n) p[i] = 0;
}

__global__ void count_kernel(const int* __restrict__ dst, int* __restrict__ deg, int E){
  int i = blockIdx.x * blockDim.x + threadIdx.x;
  if (i < E) atomicAdd(&deg[dst[i]], 1);
}

__global__ void scan_kernel(const int* __restrict__ deg, int* __restrict__ offs, int n){
  __shared__ int sh[1024];
  __shared__ int carry;
  int tid = threadIdx.x;
  if (tid == 0){ carry = 0; offs[0] = 0; }
  __syncthreads();
  for (int base = 0; base < n; base += 1024){
    int i = base + tid;
    int v = (i < n) ? deg[i] : 0;
    sh[tid] = v;
    __syncthreads();
    for (int o = 1; o < 1024; o <<= 1){
      int t = (tid >= o) ? sh[tid - o] : 0;
      __syncthreads();
      sh[tid] += t;
      __syncthreads();
    }
    int c = carry;
    int inc = sh[tid];
    int total = sh[1023];
    if (i < n) offs[i + 1] = c + inc;
    __syncthreads();
    if (tid == 0) carry = c + total;
    __syncthreads();
  }
}

__global__ void scatter_kernel(const int* __restrict__ src, const int* __restrict__ dst,
                               const int* __restrict__ et, const int* __restrict__ offs,
                               int* __restrict__ cursor, int* __restrict__ csr_src,
                               int* __restrict__ csr_et, int E){
  int i = blockIdx.x * blockDim.x + threadIdx.x;
  if (i < E){
    int d = dst[i];
    int pos = offs[d] + atomicAdd(&cursor[d], 1);
    csr_src[pos] = src[i];
    csr_et[pos]  = et[i];
  }
}

// ---------------- relation-weight precombine: Wr[r] = sum_b comp[r,b]*basis[b]; Wr[8] = root ----

__global__ void relw_kernel(const float* __restrict__ basis, const float* __restrict__ comp,
                            const float* __restrict__ root, float* __restrict__ Wr, int fin){
  int idx = blockIdx.x * 256 + threadIdx.x;
  int total = 9 * fin * 64;
  if (idx >= total) return;
  int r = idx / (fin * 64);
  int rem = idx - r * fin * 64;
  if (r == 8){ Wr[idx] = root[rem]; return; }
  float s = 0.f;
  #pragma unroll
  for (int b = 0; b < 4; b++) s += comp[r * 4 + b] * basis[(size_t)b * fin * 64 + rem];
  Wr[idx] = s;
}

// ---------------- register-blocked GEMM: Y[n, cg*64+c] = sum_k X[n,k] * W[k, cg*64+c] ----
// thread = row (node), blockIdx.y = column group cg (64 cols), acc[64] in VGPRs.
// W row addresses are wave-uniform -> broadcast loads.
// Optionally fuses the GAT attention logits (cols of group cg = channels of head cg).

template<int FIN, bool ATT>
__global__ __launch_bounds__(256) void gemm_cols64_kernel(
    const float* __restrict__ X, const float* __restrict__ Wb,
    int wstride, int wblock, int ostride,
    const float* __restrict__ atts, const float* __restrict__ attd,
    float* __restrict__ Y, float* __restrict__ as_, float* __restrict__ ad_)
{
  int node = blockIdx.x * 256 + threadIdx.x;
  int cg = blockIdx.y;
  if (node >= NN) return;
  const float* W  = Wb + (size_t)cg * wblock;
  const float* xr = X + (size_t)node * FIN;
  float acc[64];
  #pragma unroll
  for (int c = 0; c < 64; c++) acc[c] = 0.f;
  for (int k0 = 0; k0 < FIN; k0 += 16){
    float xv[16];
    #pragma unroll
    for (int j = 0; j < 4; j++){
      float4 v = *(const float4*)(xr + k0 + j * 4);
      xv[j*4] = v.x; xv[j*4+1] = v.y; xv[j*4+2] = v.z; xv[j*4+3] = v.w;
    }
    #pragma unroll 4
    for (int kk = 0; kk < 16; kk++){
      const float* Wr = W + (size_t)(k0 + kk) * wstride;
      float xk = xv[kk];
      #pragma unroll
      for (int c = 0; c < 64; c += 4){
        float4 bv = *(const float4*)(Wr + c);
        acc[c]   += xk * bv.x;
        acc[c+1] += xk * bv.y;
        acc[c+2] += xk * bv.z;
        acc[c+3] += xk * bv.w;
      }
    }
  }
  float* yr = Y + (size_t)node * ostride + cg * 64;
  #pragma unroll
  for (int c = 0; c < 64; c += 4)
    *(float4*)(yr + c) = make_float4(acc[c], acc[c+1], acc[c+2], acc[c+3]);
  if (ATT){
    float ps = 0.f, pd = 0.f;
    const float* pa = atts + cg * 64;
    const float* pb = attd + cg * 64;
    #pragma unroll
    for (int c = 0; c < 64; c++){ ps += acc[c] * pa[c]; pd += acc[c] * pb[c]; }
    as_[node * 4 + cg] = ps;
    ad_[node * 4 + cg] = pd;
  }
}

// ---------------- RGCN aggregate ----------------
// xr layout: [n, 9*64]; slots 0..7 = per-relation transform, slot 8 = root transform.
// one wave per node: acc = mean_edges xr[src, et, :] + xr[n, 8, :] + bias, elu.

__global__ void rgcn_agg_kernel(const float* __restrict__ xr, const float* __restrict__ brg,
                                const int* __restrict__ offs, const int* __restrict__ csr_src,
                                const int* __restrict__ csr_et, float* __restrict__ hout){
  int wid  = (blockIdx.x * blockDim.x + threadIdx.x) >> 6;
  int lane = threadIdx.x & 63;
  if (wid >= NN) return;
  int n0 = offs[wid], n1 = offs[wid + 1];
  float acc = 0.f;
  int k = n0;
  for (; k + 3 < n1; k += 4){
    int s0 = csr_src[k],     e0 = csr_et[k];
    int s1 = csr_src[k + 1], e1 = csr_et[k + 1];
    int s2 = csr_src[k + 2], e2 = csr_et[k + 2];
    int s3 = csr_src[k + 3], e3 = csr_et[k + 3];
    float v0 = xr[(size_t)s0 * 576 + (e0 << 6) + lane];
    float v1 = xr[(size_t)s1 * 576 + (e1 << 6) + lane];
    float v2 = xr[(size_t)s2 * 576 + (e2 << 6) + lane];
    float v3 = xr[(size_t)s3 * 576 + (e3 << 6) + lane];
    acc += v0 + v1 + v2 + v3;
  }
  for (; k < n1; k++){
    int s = csr_src[k], e = csr_et[k];
    acc += xr[(size_t)s * 576 + (e << 6) + lane];
  }
  int dg = n1 - n0;
  acc /= (float)(dg > 0 ? dg : 1);
  acc += xr[(size_t)wid * 576 + 512 + lane];   // root term
  acc += brg[lane];
  hout[(size_t)wid * 64 + lane] = eluf(acc);
}

// ---------------- GAT ----------------

// GAT1 softmax-aggregate. one wave per (node, head): lane = channel within head.
__global__ void gat1_agg_kernel(const float* __restrict__ hw, const float* __restrict__ as_,
                                const float* __restrict__ ad_, const float* __restrict__ bias,
                                const int* __restrict__ offs, const int* __restrict__ csr_src,
                                float* __restrict__ out){
  int wid  = (blockIdx.x * blockDim.x + threadIdx.x) >> 6;
  int lane = threadIdx.x & 63;
  if (wid >= NN * 4) return;
  int node = wid >> 2, h = wid & 3;
  int n0 = offs[node], n1 = offs[node + 1];
  float adn = ad_[node * 4 + h];
  float es  = leakyf(as_[node * 4 + h] + adn);
  float m = es;
  for (int k = n0 + lane; k < n1; k += 64){
    int s = csr_src[k];
    m = fmaxf(m, leakyf(as_[s * 4 + h] + adn));
  }
  #pragma unroll
  for (int o = 32; o; o >>= 1) m = fmaxf(m, __shfl_xor(m, o));
  float ps = expf(es - m);
  float den = ps;
  float a = 0.f;
  int k = n0;
  for (; k + 1 < n1; k += 2){
    int s0 = csr_src[k], s1 = csr_src[k + 1];
    float p0 = expf(leakyf(as_[s0 * 4 + h] + adn) - m);
    float p1 = expf(leakyf(as_[s1 * 4 + h] + adn) - m);
    float v0 = hw[(size_t)s0 * 256 + h * 64 + lane];
    float v1 = hw[(size_t)s1 * 256 + h * 64 + lane];
    den += p0 + p1;
    a += p0 * v0 + p1 * v1;
  }
  for (; k < n1; k++){
    int s = csr_src[k];
    float p = expf(leakyf(as_[s * 4 + h] + adn) - m);
    den += p;
    a += p * hw[(size_t)s * 256 + h * 64 + lane];
  }
  a += ps * hw[(size_t)node * 256 + h * 64 + lane];
  out[(size_t)node * 256 + h * 64 + lane] = eluf(a / den + bias[h * 64 + lane]);
}

// hW2 = h3 @ Wg2 (64 -> 12), fused logits. one wave per node, lanes 0..11 active for GEMV.
__global__ void gat_lin2_kernel(const float* __restrict__ h, const float* __restrict__ W,
                                const float* __restrict__ atts, const float* __restrict__ attd,
                                float* __restrict__ hw, float* __restrict__ as_, float* __restrict__ ad_){
  int wid  = (blockIdx.x * blockDim.x + threadIdx.x) >> 6;
  int lane = threadIdx.x & 63;
  if (wid >= NN) return;
  float acc = 0.f;
  if (lane < 12){
    const float* hr = h + (size_t)wid * 64;
    const float* Wc = W + lane;
    #pragma unroll 8
    for (int i = 0; i < 64; i++) acc += hr[i] * Wc[(size_t)i * 12];
    hw[(size_t)wid * 12 + lane] = acc;
  }
  float ts = (lane < 12) ? acc * atts[lane] : 0.f;
  float td = (lane < 12) ? acc * attd[lane] : 0.f;
  int b = (lane < 4) ? lane * 3 : 0;
  float s0 = __shfl(ts, b) + __shfl(ts, b + 1) + __shfl(ts, b + 2);
  float d0 = __shfl(td, b) + __shfl(td, b + 1) + __shfl(td, b + 2);
  if (lane < 4){ as_[wid * 4 + lane] = s0; ad_[wid * 4 + lane] = d0; }
}

// GAT2 (mean over heads) + mean over classes + tanh. one wave per node, lanes over edges.
__global__ void gat2_final_kernel(const float* __restrict__ hw, const float* __restrict__ as_,
                                  const float* __restrict__ ad_, const float* __restrict__ bg2,
                                  const int* __restrict__ offs, const int* __restrict__ csr_src,
                                  float* __restrict__ out){
  int wid  = (blockIdx.x * blockDim.x + threadIdx.x) >> 6;
  int lane = threadIdx.x & 63;
  if (wid >= NN) return;
  int n0 = offs[wid], n1 = offs[wid + 1];
  F4 adn = ld4(ad_ + (size_t)wid * 4);
  F4 asn = ld4(as_ + (size_t)wid * 4);
  F4 es{leakyf(asn.x + adn.x), leakyf(asn.y + adn.y), leakyf(asn.z + adn.z), leakyf(asn.w + adn.w)};
  F4 m = es;
  for (int k = n0 + lane; k < n1; k += 64){
    int s = csr_src[k];
    F4 a = ld4(as_ + (size_t)s * 4);
    m.x = fmaxf(m.x, leakyf(a.x + adn.x));
    m.y = fmaxf(m.y, leakyf(a.y + adn.y));
    m.z = fmaxf(m.z, leakyf(a.z + adn.z));
    m.w = fmaxf(m.w, leakyf(a.w + adn.w));
  }
  #pragma unroll
  for (int o = 32; o; o >>= 1){
    m.x = fmaxf(m.x, __shfl_xor(m.x, o));
    m.y = fmaxf(m.y, __shfl_xor(m.y, o));
    m.z = fmaxf(m.z, __shfl_xor(m.z, o));
    m.w = fmaxf(m.w, __shfl_xor(m.w, o));
  }
  F4 ps{expf(es.x - m.x), expf(es.y - m.y), expf(es.z - m.z), expf(es.w - m.w)};
  float acc[12];
  #pragma unroll
  for (int j = 0; j < 12; j++) acc[j] = 0.f;
  F4 denp{0.f, 0.f, 0.f, 0.f};
  for (int k = n0 + lane; k < n1; k += 64){
    int s = csr_src[k];
    F4 a = ld4(as_ + (size_t)s * 4);
    F4 p{expf(leakyf(a.x + adn.x) - m.x), expf(leakyf(a.y + adn.y) - m.y),
         expf(leakyf(a.z + adn.z) - m.z), expf(leakyf(a.w + adn.w) - m.w)};
    denp.x += p.x; denp.y += p.y; denp.z += p.z; denp.w += p.w;
    const float* hb = hw + (size_t)s * 12;
    F4 h0 = ld4(hb), h1 = ld4(hb + 4), h2 = ld4(hb + 8);
    acc[0] += p.x * h0.x; acc[1]  += p.x * h0.y; acc[2]  += p.x * h0.z;
    acc[3] += p.y * h0.w; acc[4]  += p.y * h1.x; acc[5]  += p.y * h1.y;
    acc[6] += p.z * h1.z; acc[7]  += p.z * h1.w; acc[8]  += p.z * h2.x;
    acc[9] += p.w * h2.y; acc[10] += p.w * h2.z; acc[11] += p.w * h2.w;
  }
  #pragma unroll
  for (int o = 32; o; o >>= 1){
    denp.x += __shfl_xor(denp.x, o);
    denp.y += __shfl_xor(denp.y, o);
    denp.z += __shfl_xor(denp.z, o);
    denp.w += __shfl_xor(denp.w, o);
    #pragma unroll
    for (int j = 0; j < 12; j++) acc[j] += __shfl_xor(acc[j], o);
  }
  if (lane == 0){
    const float* hn = hw + (size_t)wid * 12;
    float dn[4]  = {denp.x + ps.x, denp.y + ps.y, denp.z + ps.z, denp.w + ps.w};
    float psv[4] = {ps.x, ps.y, ps.z, ps.w};
    float tot = 0.f;
    #pragma unroll
    for (int h_ = 0; h_ < 4; h_++){
      #pragma unroll
      for (int c = 0; c < 3; c++){
        float num = acc[h_ * 3 + c] + psv[h_] * hn[h_ * 3 + c];
        tot += num / dn[h_];
      }
    }
    tot = tot / 12.f + (bg2[0] + bg2[1] + bg2[2]) / 3.f;
    out[wid] = tanhf(tot);
  }
}

// ---------------- launch ----------------

extern "C" void kernel_launch(void* const* d_in, const int* in_sizes, int n_in,
                              void* d_out, int out_size, void* d_ws, size_t ws_size,
                              hipStream_t stream){
  const float* x      = (const float*)d_in[0];
  const int*   ei     = (const int*)d_in[1];
  const int*   et     = (const int*)d_in[2];
  const float* basis1 = (const float*)d_in[3];
  const float* comp1  = (const float*)d_in[4];
  const float* root1  = (const float*)d_in[5];
  const float* brg1   = (const float*)d_in[6];
  const float* Wg1    = (const float*)d_in[7];
  const float* atts1  = (const float*)d_in[8];
  const float* attd1  = (const float*)d_in[9];
  const float* bg1    = (const float*)d_in[10];
  const float* basis2 = (const float*)d_in[11];
  const float* comp2  = (const float*)d_in[12];
  const float* root2  = (const float*)d_in[13];
  const float* brg2   = (const float*)d_in[14];
  const float* Wg2    = (const float*)d_in[15];
  const float* atts2  = (const float*)d_in[16];
  const float* attd2  = (const float*)d_in[17];
  const float* bg2    = (const float*)d_in[18];
  float* out = (float*)d_out;

  const int* src = ei;
  const int* dst = ei + NE;

  char* ws = (char*)d_ws;
  size_t off = 0;
  auto alloc = [&](size_t bytes) -> void* {
    void* p = ws + off;
    off = (off + bytes + 255) & ~(size_t)255;
    return p;
  };
  int*   deg     = (int*)alloc((size_t)NN * 4);
  int*   cursor  = (int*)alloc((size_t)NN * 4);
  int*   offs    = (int*)alloc((size_t)(NN + 1) * 4);
  int*   csr_src = (int*)alloc((size_t)NE * 4);
  int*   csr_et  = (int*)alloc((size_t)NE * 4);
  float* Wr1     = (float*)alloc((size_t)9 * 32 * 64 * 4);
  float* Wr2     = (float*)alloc((size_t)9 * 256 * 64 * 4);
  float* xrbuf   = (float*)alloc((size_t)NN * 576 * 4); // xr1 -> hW1 -> xr2
  float* h1      = (float*)alloc((size_t)NN * 64 * 4);
  float* h2      = (float*)alloc((size_t)NN * 256 * 4);
  float* h3      = (float*)alloc((size_t)NN * 64 * 4);
  float* hw2     = (float*)alloc((size_t)NN * 12 * 4);
  float* as1     = (float*)alloc((size_t)NN * 4 * 4);
  float* ad1     = (float*)alloc((size_t)NN * 4 * 4);
  float* as2     = (float*)alloc((size_t)NN * 4 * 4);
  float* ad2     = (float*)alloc((size_t)NN * 4 * 4);
  (void)ws_size; (void)n_in; (void)in_sizes; (void)out_size;

  const int BLK = 256;
  int gridN  = (NN + BLK - 1) / BLK;
  int gridE  = (NE + BLK - 1) / BLK;
  int gridW  = (NN + 3) / 4;            // 4 waves/block, 1 node/wave
  int gridW4 = (NN * 4 + 3) / 4;        // 4 waves/block, 1 (node,head)/wave
  dim3 gridG9((NN + 255) / 256, 9);     // rgcn GEMM: 8 relations + root
  dim3 gridG4((NN + 255) / 256, 4);     // gat1 GEMM: 4 heads

  // CSR build + relation weights
  zero_int_kernel<<<gridN, BLK, 0, stream>>>(deg, NN);
  zero_int_kernel<<<gridN, BLK, 0, stream>>>(cursor, NN);
  count_kernel<<<gridE, BLK, 0, stream>>>(dst, deg, NE);
  relw_kernel<<<(9 * 32 * 64 + 255) / 256, BLK, 0, stream>>>(basis1, comp1, root1, Wr1, 32);
  relw_kernel<<<(9 * 256 * 64 + 255) / 256, BLK, 0, stream>>>(basis2, comp2, root2, Wr2, 256);
  scan_kernel<<<1, 1024, 0, stream>>>(deg, offs, NN);
  scatter_kernel<<<gridE, BLK, 0, stream>>>(src, dst, et, offs, cursor, csr_src, csr_et, NE);

  // Layer 1: RGCN (32 -> 64) + elu
  gemm_cols64_kernel<32, false><<<gridG9, BLK, 0, stream>>>(
      x, Wr1, 64, 32 * 64, 576, nullptr, nullptr, xrbuf, nullptr, nullptr);
  rgcn_agg_kernel<<<gridW, BLK, 0, stream>>>(xrbuf, brg1, offs, csr_src, csr_et, h1);

  // Layer 2: GAT (64 -> 256 concat) + elu  (linear fused with attention logits)
  gemm_cols64_kernel<64, true><<<gridG4, BLK, 0, stream>>>(
      h1, Wg1, 256, 64, 256, atts1, attd1, xrbuf, as1, ad1);
  gat1_agg_kernel<<<gridW4, BLK, 0, stream>>>(xrbuf, as1, ad1, bg1, offs, csr_src, h2);

  // Layer 3: RGCN (256 -> 64) + elu
  gemm_cols64_kernel<256, false><<<gridG9, BLK, 0, stream>>>(
      h2, Wr2, 64, 256 * 64, 576, nullptr, nullptr, xrbuf, nullptr, nullptr);
  rgcn_agg_kernel<<<gridW, BLK, 0, stream>>>(xrbuf, brg2, offs, csr_src, csr_et, h3);

  // Layer 4: GAT (64 -> 4x3, mean heads) + mean classes + tanh
  gat_lin2_kernel<<<gridW, BLK, 0, stream>>>(h3, Wg2, atts2, attd2, hw2, as2, ad2);
  gat2_final_kernel<<<gridW, BLK, 0, stream>>>(hw2, as2, ad2, bg2, offs, csr_src, out);
}